// Round 9
// baseline (366.571 us; speedup 1.0000x reference)
//
#include <hip/hip_runtime.h>
#include <cmath>

#define FILT 11

typedef float v2f __attribute__((ext_vector_type(2)));

struct GW { float w[FILT]; };

// ---- order-preserving float<->uint encode for atomic min/max ----
__device__ __forceinline__ unsigned enc_f(float f) {
    unsigned u = __float_as_uint(f);
    return (u & 0x80000000u) ? ~u : (u | 0x80000000u);
}
__device__ __forceinline__ float dec_f(unsigned u) {
    return (u & 0x80000000u) ? __uint_as_float(u & 0x7FFFFFFFu)
                             : __uint_as_float(~u);
}

__global__ void init_acc(unsigned* ws) {
    int t = threadIdx.x;
    if (t == 0) { ws[0] = 0u; ws[1] = 0xFFFFFFFFu; }
    for (int i = 2 + t; i < 512; i += blockDim.x) ws[i] = 0u;  // float 0.0
}

__global__ void minmax_kernel(const float4* __restrict__ t, long n4, unsigned* mm) {
    unsigned mx = 0u, mn = 0xFFFFFFFFu;
    long stride = (long)gridDim.x * blockDim.x;
    for (long i = (long)blockIdx.x * blockDim.x + threadIdx.x; i < n4; i += stride) {
        float4 v = t[i];
        unsigned a = enc_f(v.x), b = enc_f(v.y), c = enc_f(v.z), d = enc_f(v.w);
        mx = max(mx, max(max(a, b), max(c, d)));
        mn = min(mn, min(min(a, b), min(c, d)));
    }
    for (int off = 32; off; off >>= 1) {
        mx = max(mx, (unsigned)__shfl_down((int)mx, off));
        mn = min(mn, (unsigned)__shfl_down((int)mn, off));
    }
    __shared__ unsigned smx[4], smn[4];
    int wid = threadIdx.x >> 6, lane = threadIdx.x & 63;
    if (lane == 0) { smx[wid] = mx; smn[wid] = mn; }
    __syncthreads();
    if (threadIdx.x == 0) {
        for (int i = 1; i < 4; i++) { mx = max(mx, smx[i]); mn = min(mn, smn[i]); }
        atomicMax(&mm[0], mx);
        atomicMin(&mm[1], mn);
    }
}

// Row-streaming fused SSIM + pool. One wave owns a 64-out-col strip x row band.
// 2-deep register prefetch (load row r+3 at iter r), parity-selected reg sets.
// NO explicit lgkmcnt drain: same-wave LDS ops are in-order; compiler inserts
// counted waits on tap-read dests. Trip-11 body keeps I-cache small and all
// acc[] ring indices compile-time (VGPRs, not scratch).
__global__ __launch_bounds__(256) void ssim_stream(
    const float* __restrict__ x, const float* __restrict__ y,
    int H, int W, int NC, int nstrips, int nb, int B,
    const unsigned* __restrict__ mm,
    float* __restrict__ cs_sum, float* __restrict__ ssim_sum, GW gw,
    float* __restrict__ poolx, float* __restrict__ pooly, int do_pool)
{
    __shared__ v2f ring[4][2][80];

    const int wv = threadIdx.x >> 6;
    const int lane = threadIdx.x & 63;
    const int wid = blockIdx.x * 4 + wv;
    const int total = NC * nstrips * nb;
    if (wid >= total) return;

    const int band = wid % nb;
    const int t1 = wid / nb;
    const int strip = t1 % nstrips;
    const int img = t1 / nstrips;
    const int n = img / 3;

    const int Ho = H - (FILT - 1);
    const int Wo = W - (FILT - 1);
    const int out_lo = band * B;
    const int out_hi = min(out_lo + B, Ho);
    if (out_lo >= Ho) return;
    const int a = out_lo, b = out_hi + (FILT - 1);  // input rows [a, b)

    const int base = strip * 64;
    const float* xp = x + (size_t)img * H * W;
    const float* yp = y + (size_t)img * H * W;
    const int c0 = min(base + lane, W - 1);
    const int c1 = min(base + 64 + lane, W - 1);
    const bool colv = (base + lane) < Wo;

    const float mv = dec_f(mm[0]) - dec_f(mm[1]);
    const float c1c = (0.01f * mv) * (0.01f * mv);
    const float c2c = (0.03f * mv) * (0.03f * mv);

    const int Wp = W >> 1;
    const size_t pbase = (size_t)img * (H >> 1) * Wp;

    // packed accumulators: acc01 = (mu1,mu2), acc23 = (E[xx],E[yy]), acc4 = E[xy]
    v2f acc01[FILT], acc23[FILT];
    float acc4[FILT];
#pragma unroll
    for (int s = 0; s < FILT; s++) {
        acc01[s] = (v2f){0.f, 0.f};
        acc23[s] = (v2f){0.f, 0.f};
        acc4[s] = 0.f;
    }

    float lcs = 0.f, lss = 0.f;

    // ---- prologue ----
    // row a -> LDS ring[a&1]; row a+1 -> reg set of parity (a+1)&1;
    // row a+2 -> reg set of parity a&1. Pointers end at row a+3.
    // (band rows b-a >= 16 for all levels, so rows a+1, a+2 exist)
    float ox0, oy0, ox1, oy1;   // set holding rows of parity 1
    float ex0, ey0, ex1, ey1;   // set holding rows of parity 0
    {
        const float* xr0 = xp + (size_t)a * W;
        const float* yr0 = yp + (size_t)a * W;
        float t0 = xr0[c0], t1 = yr0[c0];
        float t2 = xr0[c1], t3 = yr0[c1];
        v2f* buf0 = &ring[wv][a & 1][0];
        buf0[lane] = (v2f){t0, t1};
        if (lane < 10) buf0[64 + lane] = (v2f){t2, t3};
        const float* xr1 = xr0 + W;
        const float* yr1 = yr0 + W;
        const float* xr2 = xr0 + 2 * (size_t)W;
        const float* yr2 = yr0 + 2 * (size_t)W;
        if ((a + 1) & 1) {
            ox0 = xr1[c0]; oy0 = yr1[c0]; ox1 = xr1[c1]; oy1 = yr1[c1];
            ex0 = xr2[c0]; ey0 = yr2[c0]; ex1 = xr2[c1]; ey1 = yr2[c1];
        } else {
            ex0 = xr1[c0]; ey0 = yr1[c0]; ex1 = xr1[c1]; ey1 = yr1[c1];
            ox0 = xr2[c0]; oy0 = yr2[c0]; ox1 = xr2[c1]; oy1 = yr2[c1];
        }
    }
    const float* xr = xp + (size_t)min(a + 3, b - 1) * W;
    const float* yr = yp + (size_t)min(a + 3, b - 1) * W;

#pragma unroll 1
    for (int r0 = a; r0 < b; r0 += FILT) {
#pragma unroll
        for (int p = 0; p < FILT; p++) {      // fixed trip count, NO break
            const int r = r0 + p;
            if (r < b) {
                const int cur = r & 1;
                v2f* bufc = &ring[wv][cur][0];        // row r
                v2f* bufn = &ring[wv][cur ^ 1][0];    // row r-1 -> gets row r+1

                // ---- fused 2x2 avg pool on raw rows (r-1, r), before overwrite ----
                if (do_pool && (r & 1) && r > a && lane < 32) {
                    const int pc = (base >> 1) + lane;
                    if (pc < Wp) {
                        v2f q00 = bufn[2 * lane];
                        v2f q01 = bufn[2 * lane + 1];
                        v2f q10 = bufc[2 * lane];
                        v2f q11 = bufc[2 * lane + 1];
                        v2f sm = (q00 + q01 + q10 + q11) * (v2f){0.25f, 0.25f};
                        size_t o = pbase + (size_t)(r >> 1) * Wp + pc;
                        poolx[o] = sm.x;
                        pooly[o] = sm.y;
                    }
                }

                // ---- stage row r+1 (parity set) then load row r+3 into it ----
                if ((r + 1) & 1) {
                    if (r + 1 < b) {
                        bufn[lane] = (v2f){ox0, oy0};
                        if (lane < 10) bufn[64 + lane] = (v2f){ox1, oy1};
                    }
                    ox0 = xr[c0]; oy0 = yr[c0];
                    ox1 = xr[c1]; oy1 = yr[c1];
                } else {
                    if (r + 1 < b) {
                        bufn[lane] = (v2f){ex0, ey0};
                        if (lane < 10) bufn[64 + lane] = (v2f){ex1, ey1};
                    }
                    ex0 = xr[c0]; ey0 = yr[c0];
                    ex1 = xr[c1]; ey1 = yr[c1];
                }
                if (r + 4 < b) { xr += W; yr += W; }

                // ---- horizontal 11-tap blur of row r, channels packed ----
                v2f h01 = (v2f){0.f, 0.f};
                v2f h23 = (v2f){0.f, 0.f};
                float h4 = 0.f;
#pragma unroll
                for (int k = 0; k < FILT; k++) {
                    v2f v = bufc[lane + k];
                    float w = gw.w[k];
                    v2f w2 = {w, w};
                    h01 = __builtin_elementwise_fma(w2, v, h01);         // pk_fma
                    v2f sq = v * v;                                      // pk_mul
                    h23 = __builtin_elementwise_fma(w2, sq, h23);        // pk_fma
                    h4 = __builtin_fmaf(w, v.x * v.y, h4);
                }

                // ---- vertical ring accumulation (all indices static) ----
#pragma unroll
                for (int k = 0; k < FILT; k++) {
                    const int s = (p - k + FILT) % FILT;
                    float w = gw.w[k];
                    v2f w2 = {w, w};
                    acc01[s] = __builtin_elementwise_fma(w2, h01, acc01[s]);
                    acc23[s] = __builtin_elementwise_fma(w2, h23, acc23[s]);
                    acc4[s] = __builtin_fmaf(w, h4, acc4[s]);
                }

                // ---- emit completed output row ro = r-10 (slot e) ----
                const int e = (p + 1) % FILT;
                if (r >= a + (FILT - 1) && colv) {
                    float m1 = acc01[e].x, m2 = acc01[e].y;
                    float mu11 = m1 * m1, mu22 = m2 * m2, mu12 = m1 * m2;
                    float s1 = acc23[e].x - mu11;
                    float s2 = acc23[e].y - mu22;
                    float s12 = acc4[e] - mu12;
                    // cs = A/Bv, ss = (Cv/Dv)*cs  -> one v_rcp via r_=rcp(Bv*Dv)
                    float A = 2.f * s12 + c2c, Bv = s1 + s2 + c2c;
                    float Cv = 2.f * mu12 + c1c, Dv = mu11 + mu22 + c1c;
                    float r_ = __builtin_amdgcn_rcpf(Bv * Dv);
                    lcs += A * Dv * r_;
                    lss += Cv * A * r_;
                }
                acc01[e] = (v2f){0.f, 0.f};
                acc23[e] = (v2f){0.f, 0.f};
                acc4[e] = 0.f;
            }
        }
    }

    // ---- per-wave reduction + atomic ----
    for (int off = 32; off; off >>= 1) {
        lcs += __shfl_down(lcs, off);
        lss += __shfl_down(lss, off);
    }
    if (lane == 0) {
        atomicAdd(&cs_sum[n], lcs);
        atomicAdd(&ssim_sum[n], lss);
    }
}

__global__ void final_kernel(const float* __restrict__ cs_sum,
                             const float* __restrict__ ssim_sum,
                             float* __restrict__ out)
{
    const float cnt[5] = {3.f * 502 * 502, 3.f * 246 * 246, 3.f * 118 * 118,
                          3.f * 54 * 54, 3.f * 22 * 22};
    const float wts[5] = {0.0448f, 0.2856f, 0.3001f, 0.2363f, 0.1333f};
    int n = threadIdx.x;
    float ms = 0.f;
    if (n < 32) {
        float ssim = ssim_sum[4 * 32 + n] / cnt[4];
        float t = powf(ssim, wts[4]);
        ms = 1.f;
        for (int l = 0; l < 4; l++) {
            float cs = cs_sum[l * 32 + n] / cnt[l];
            ms *= powf(cs, wts[l]) * t;  // faithful: ssim^w4 inside the product
        }
    }
    for (int off = 32; off; off >>= 1) ms += __shfl_down(ms, off);
    if (threadIdx.x == 0) out[0] = ms / 32.f;
}

extern "C" void kernel_launch(void* const* d_in, const int* in_sizes, int n_in,
                              void* d_out, int out_size, void* d_ws, size_t ws_size,
                              hipStream_t stream) {
    const float* x0 = (const float*)d_in[0];
    const float* y0 = (const float*)d_in[1];
    float* out = (float*)d_out;
    float* ws = (float*)d_ws;
    unsigned* mm = (unsigned*)d_ws;
    float* cs_sum = ws + 2;
    float* ssim_sum = ws + 2 + 5 * 32;

    const int N = 32, C = 3, NC = N * C;
    const int Hs[5] = {512, 256, 128, 64, 32};
    // L0: nb=4 -> halo 7.4%, 3072 waves (~= observed resident cap 11-12/CU)
    // L1: nb=6 -> halo 20%, 2304 waves; L2-L4 as R8
    const int NBs[5] = {4, 6, 10, 6, 3};

    // pyramid buffers in ws (floats), after 512-float accumulator area
    float* wp = ws + 512;
    float* pxw[5] = {nullptr, nullptr, nullptr, nullptr, nullptr};
    float* pyw[5] = {nullptr, nullptr, nullptr, nullptr, nullptr};
    for (int l = 1; l < 5; l++) {
        size_t sz = (size_t)NC * Hs[l] * Hs[l];
        pxw[l] = wp; wp += sz;
        pyw[l] = wp; wp += sz;
    }
    const float* px[5] = {x0, pxw[1], pxw[2], pxw[3], pxw[4]};
    const float* py[5] = {y0, pyw[1], pyw[2], pyw[3], pyw[4]};

    // gaussian weights (softmax of -c^2/(2*sigma^2))
    GW gw;
    {
        double tmp[FILT], s = 0.0;
        for (int k = 0; k < FILT; k++) {
            double c = (double)k - (FILT - 1) / 2.0;
            tmp[k] = exp(-c * c / (2.0 * 1.5 * 1.5));
            s += tmp[k];
        }
        for (int k = 0; k < FILT; k++) gw.w[k] = (float)(tmp[k] / s);
    }

    init_acc<<<1, 256, 0, stream>>>(mm);
    long n4 = (long)NC * 512 * 512 / 4;
    minmax_kernel<<<2048, 256, 0, stream>>>((const float4*)y0, n4, mm);

    for (int l = 0; l < 5; l++) {
        int H = Hs[l];
        int Ho = H - (FILT - 1);
        int nstrips = (Ho + 63) / 64;
        int nb = NBs[l];
        int B = (Ho + nb - 1) / nb;
        nb = (Ho + B - 1) / B;
        int total_waves = NC * nstrips * nb;
        int grid = (total_waves + 3) / 4;
        int do_pool = (l < 4) ? 1 : 0;
        ssim_stream<<<grid, 256, 0, stream>>>(
            px[l], py[l], H, H, NC, nstrips, nb, B, mm,
            cs_sum + l * 32, ssim_sum + l * 32, gw,
            do_pool ? pxw[l + 1] : nullptr,
            do_pool ? pyw[l + 1] : nullptr, do_pool);
    }
    final_kernel<<<1, 64, 0, stream>>>(cs_sum, ssim_sum, out);
}

// Round 10
// 329.045 us; speedup vs baseline: 1.1140x; 1.1140x over previous
//
#include <hip/hip_runtime.h>
#include <cmath>

#define FILT 11

typedef float v2f __attribute__((ext_vector_type(2)));

struct GW { float w[FILT]; };

// ---- order-preserving float<->uint encode for atomic min/max ----
__device__ __forceinline__ unsigned enc_f(float f) {
    unsigned u = __float_as_uint(f);
    return (u & 0x80000000u) ? ~u : (u | 0x80000000u);
}
__device__ __forceinline__ float dec_f(unsigned u) {
    return (u & 0x80000000u) ? __uint_as_float(u & 0x7FFFFFFFu)
                             : __uint_as_float(~u);
}

__global__ void init_acc(unsigned* ws) {
    int t = threadIdx.x;
    if (t == 0) { ws[0] = 0u; ws[1] = 0xFFFFFFFFu; }
    for (int i = 2 + t; i < 512; i += blockDim.x) ws[i] = 0u;  // float 0.0
}

__global__ void minmax_kernel(const float4* __restrict__ t, long n4, unsigned* mm) {
    unsigned mx = 0u, mn = 0xFFFFFFFFu;
    long stride = (long)gridDim.x * blockDim.x;
    for (long i = (long)blockIdx.x * blockDim.x + threadIdx.x; i < n4; i += stride) {
        float4 v = t[i];
        unsigned a = enc_f(v.x), b = enc_f(v.y), c = enc_f(v.z), d = enc_f(v.w);
        mx = max(mx, max(max(a, b), max(c, d)));
        mn = min(mn, min(min(a, b), min(c, d)));
    }
    for (int off = 32; off; off >>= 1) {
        mx = max(mx, (unsigned)__shfl_down((int)mx, off));
        mn = min(mn, (unsigned)__shfl_down((int)mn, off));
    }
    __shared__ unsigned smx[4], smn[4];
    int wid = threadIdx.x >> 6, lane = threadIdx.x & 63;
    if (lane == 0) { smx[wid] = mx; smn[wid] = mn; }
    __syncthreads();
    if (threadIdx.x == 0) {
        for (int i = 1; i < 4; i++) { mx = max(mx, smx[i]); mn = min(mn, smn[i]); }
        atomicMax(&mm[0], mx);
        atomicMin(&mm[1], mn);
    }
}

// Row-streaming fused SSIM + pool, DOUBLE-ROW steps. One wave owns a
// 64-out-col strip x row band; bands start at even rows (B even).
// Per step: stage rows (r,r+1) -> prefetch rows (r+2,r+3) -> pool(r,r+1)
// -> 22 tap reads -> two h-chains -> vertical ring x2 -> emit x2.
// All acc/phase indices compile-time (trip-11 double-step, no break).
__global__ __launch_bounds__(256) void ssim_stream(
    const float* __restrict__ x, const float* __restrict__ y,
    int H, int W, int NC, int nstrips, int nb, int B,
    const unsigned* __restrict__ mm,
    float* __restrict__ cs_sum, float* __restrict__ ssim_sum, GW gw,
    float* __restrict__ poolx, float* __restrict__ pooly, int do_pool)
{
    __shared__ v2f ring[4][2][80];

    const int wv = threadIdx.x >> 6;
    const int lane = threadIdx.x & 63;
    const int wid = blockIdx.x * 4 + wv;
    const int total = NC * nstrips * nb;
    if (wid >= total) return;

    const int band = wid % nb;
    const int t1 = wid / nb;
    const int strip = t1 % nstrips;
    const int img = t1 / nstrips;
    const int n = img / 3;

    const int Ho = H - (FILT - 1);
    const int Wo = W - (FILT - 1);
    const int a = band * B;                 // even (B even)
    if (a >= Ho) return;
    const int out_hi = min(a + B, Ho);
    const int bEnd = out_hi + (FILT - 1);   // input rows [a, bEnd)

    const int base = strip * 64;
    const float* xp = x + (size_t)img * H * W;
    const float* yp = y + (size_t)img * H * W;
    const int c0 = min(base + lane, W - 1);
    const int c1 = min(base + 64 + min(lane, 9), W - 1);  // halo: 1 cacheline
    const bool colv = (base + lane) < Wo;

    const float mv = dec_f(mm[0]) - dec_f(mm[1]);
    const float c1c = (0.01f * mv) * (0.01f * mv);
    const float c2c = (0.03f * mv) * (0.03f * mv);

    const int Wp = W >> 1;
    const size_t pbase = (size_t)img * (H >> 1) * Wp;

    v2f* bufE = &ring[wv][0][0];   // even rows
    v2f* bufO = &ring[wv][1][0];   // odd rows

    // packed accumulators: acc01=(mu1,mu2), acc23=(E[xx],E[yy]), acc4=E[xy]
    v2f acc01[FILT], acc23[FILT];
    float acc4[FILT];
#pragma unroll
    for (int s = 0; s < FILT; s++) {
        acc01[s] = (v2f){0.f, 0.f};
        acc23[s] = (v2f){0.f, 0.f};
        acc4[s] = 0.f;
    }

    float lcs = 0.f, lss = 0.f;

    // ---- prologue: prefetch rows a, a+1 into registers ----
    float ex0, ey0, ex1, ey1, ox0, oy0, ox1, oy1;
    {
        const float* xe = xp + (size_t)a * W;
        const float* ye = yp + (size_t)a * W;
        ex0 = xe[c0]; ey0 = ye[c0]; ex1 = xe[c1]; ey1 = ye[c1];
        ox0 = xe[W + c0]; oy0 = ye[W + c0];
        ox1 = xe[W + c1]; oy1 = ye[W + c1];
    }

#pragma unroll 1
    for (int r0 = a; r0 < bEnd; r0 += 22) {
#pragma unroll
        for (int p = 0; p < FILT; p++) {     // 11 double-steps, NO break
            const int r = r0 + 2 * p;
            if (r < bEnd) {
                const bool hasO = (r + 1 < bEnd);
                const int pe = (2 * p) % FILT;        // compile-time
                const int po = (2 * p + 1) % FILT;    // compile-time

                // ---- stage rows r, r+1 into LDS (same-wave DS is in-order) ----
                bufE[lane] = (v2f){ex0, ey0};
                if (lane < 10) bufE[64 + lane] = (v2f){ex1, ey1};
                if (hasO) {
                    bufO[lane] = (v2f){ox0, oy0};
                    if (lane < 10) bufO[64 + lane] = (v2f){ox1, oy1};
                }

                // ---- issue global loads for rows r+2, r+3 (clamped) ----
                {
                    const int re = min(r + 2, bEnd - 1);
                    const int ro = min(r + 3, bEnd - 1);
                    const float* xe = xp + (size_t)re * W;
                    const float* ye = yp + (size_t)re * W;
                    const float* xo = xp + (size_t)ro * W;
                    const float* yo = yp + (size_t)ro * W;
                    ex0 = xe[c0]; ey0 = ye[c0]; ex1 = xe[c1]; ey1 = ye[c1];
                    ox0 = xo[c0]; oy0 = yo[c0]; ox1 = xo[c1]; oy1 = yo[c1];
                }

                // ---- fused 2x2 avg pool on pair (r, r+1); dups idempotent ----
                if (do_pool && hasO && lane < 32) {
                    const int pc = (base >> 1) + lane;
                    if (pc < Wp) {
                        float4 qe = *(const float4*)&bufE[2 * lane];
                        float4 qo = *(const float4*)&bufO[2 * lane];
                        size_t o = pbase + (size_t)(r >> 1) * Wp + pc;
                        poolx[o] = 0.25f * (qe.x + qe.z + qo.x + qo.z);
                        pooly[o] = 0.25f * (qe.y + qe.w + qo.y + qo.w);
                    }
                }

                // ---- horizontal 11-tap blur, row r (and r+1), packed ----
                v2f h01e = (v2f){0.f, 0.f}, h23e = (v2f){0.f, 0.f};
                float h4e = 0.f;
#pragma unroll
                for (int k = 0; k < FILT; k++) {
                    v2f v = bufE[lane + k];
                    float w = gw.w[k];
                    v2f w2 = {w, w};
                    h01e = __builtin_elementwise_fma(w2, v, h01e);
                    v2f sq = v * v;
                    h23e = __builtin_elementwise_fma(w2, sq, h23e);
                    h4e = __builtin_fmaf(w, v.x * v.y, h4e);
                }

                // ---- vertical ring add, row r (phase pe) ----
#pragma unroll
                for (int k = 0; k < FILT; k++) {
                    const int s = (pe - k + FILT) % FILT;
                    float w = gw.w[k];
                    v2f w2 = {w, w};
                    acc01[s] = __builtin_elementwise_fma(w2, h01e, acc01[s]);
                    acc23[s] = __builtin_elementwise_fma(w2, h23e, acc23[s]);
                    acc4[s] = __builtin_fmaf(w, h4e, acc4[s]);
                }

                // ---- emit output row r-10 (slot eE) ----
                const int eE = (pe + 1) % FILT;
                if (r >= a + (FILT - 1) && colv) {
                    float m1 = acc01[eE].x, m2 = acc01[eE].y;
                    float mu11 = m1 * m1, mu22 = m2 * m2, mu12 = m1 * m2;
                    float s1 = acc23[eE].x - mu11;
                    float s2 = acc23[eE].y - mu22;
                    float s12 = acc4[eE] - mu12;
                    float A = 2.f * s12 + c2c, Bv = s1 + s2 + c2c;
                    float Cv = 2.f * mu12 + c1c, Dv = mu11 + mu22 + c1c;
                    float r_ = __builtin_amdgcn_rcpf(Bv * Dv);
                    lcs += A * Dv * r_;
                    lss += Cv * A * r_;
                }
                acc01[eE] = (v2f){0.f, 0.f};
                acc23[eE] = (v2f){0.f, 0.f};
                acc4[eE] = 0.f;

                if (hasO) {
                    v2f h01o = (v2f){0.f, 0.f}, h23o = (v2f){0.f, 0.f};
                    float h4o = 0.f;
#pragma unroll
                    for (int k = 0; k < FILT; k++) {
                        v2f v = bufO[lane + k];
                        float w = gw.w[k];
                        v2f w2 = {w, w};
                        h01o = __builtin_elementwise_fma(w2, v, h01o);
                        v2f sq = v * v;
                        h23o = __builtin_elementwise_fma(w2, sq, h23o);
                        h4o = __builtin_fmaf(w, v.x * v.y, h4o);
                    }
#pragma unroll
                    for (int k = 0; k < FILT; k++) {
                        const int s = (po - k + FILT) % FILT;
                        float w = gw.w[k];
                        v2f w2 = {w, w};
                        acc01[s] = __builtin_elementwise_fma(w2, h01o, acc01[s]);
                        acc23[s] = __builtin_elementwise_fma(w2, h23o, acc23[s]);
                        acc4[s] = __builtin_fmaf(w, h4o, acc4[s]);
                    }
                    const int eO = (po + 1) % FILT;
                    if (r >= a + (FILT - 1) && colv) {   // r+1 >= a+10 <=> r >= a+10 (even step)
                        float m1 = acc01[eO].x, m2 = acc01[eO].y;
                        float mu11 = m1 * m1, mu22 = m2 * m2, mu12 = m1 * m2;
                        float s1 = acc23[eO].x - mu11;
                        float s2 = acc23[eO].y - mu22;
                        float s12 = acc4[eO] - mu12;
                        float A = 2.f * s12 + c2c, Bv = s1 + s2 + c2c;
                        float Cv = 2.f * mu12 + c1c, Dv = mu11 + mu22 + c1c;
                        float r_ = __builtin_amdgcn_rcpf(Bv * Dv);
                        lcs += A * Dv * r_;
                        lss += Cv * A * r_;
                    }
                    acc01[eO] = (v2f){0.f, 0.f};
                    acc23[eO] = (v2f){0.f, 0.f};
                    acc4[eO] = 0.f;
                }
            }
        }
    }

    // ---- per-wave reduction + atomic ----
    for (int off = 32; off; off >>= 1) {
        lcs += __shfl_down(lcs, off);
        lss += __shfl_down(lss, off);
    }
    if (lane == 0) {
        atomicAdd(&cs_sum[n], lcs);
        atomicAdd(&ssim_sum[n], lss);
    }
}

__global__ void final_kernel(const float* __restrict__ cs_sum,
                             const float* __restrict__ ssim_sum,
                             float* __restrict__ out)
{
    const float cnt[5] = {3.f * 502 * 502, 3.f * 246 * 246, 3.f * 118 * 118,
                          3.f * 54 * 54, 3.f * 22 * 22};
    const float wts[5] = {0.0448f, 0.2856f, 0.3001f, 0.2363f, 0.1333f};
    int n = threadIdx.x;
    float ms = 0.f;
    if (n < 32) {
        float ssim = ssim_sum[4 * 32 + n] / cnt[4];
        float t = powf(ssim, wts[4]);
        ms = 1.f;
        for (int l = 0; l < 4; l++) {
            float cs = cs_sum[l * 32 + n] / cnt[l];
            ms *= powf(cs, wts[l]) * t;  // faithful: ssim^w4 inside the product
        }
    }
    for (int off = 32; off; off >>= 1) ms += __shfl_down(ms, off);
    if (threadIdx.x == 0) out[0] = ms / 32.f;
}

extern "C" void kernel_launch(void* const* d_in, const int* in_sizes, int n_in,
                              void* d_out, int out_size, void* d_ws, size_t ws_size,
                              hipStream_t stream) {
    const float* x0 = (const float*)d_in[0];
    const float* y0 = (const float*)d_in[1];
    float* out = (float*)d_out;
    float* ws = (float*)d_ws;
    unsigned* mm = (unsigned*)d_ws;
    float* cs_sum = ws + 2;
    float* ssim_sum = ws + 2 + 5 * 32;

    const int N = 32, C = 3, NC = N * C;
    const int Hs[5] = {512, 256, 128, 64, 32};
    // per-level band heights (EVEN, so bands start at even rows)
    const int Bs[5] = {64, 42, 12, 10, 8};

    // pyramid buffers in ws (floats), after 512-float accumulator area
    float* wp = ws + 512;
    float* pxw[5] = {nullptr, nullptr, nullptr, nullptr, nullptr};
    float* pyw[5] = {nullptr, nullptr, nullptr, nullptr, nullptr};
    for (int l = 1; l < 5; l++) {
        size_t sz = (size_t)NC * Hs[l] * Hs[l];
        pxw[l] = wp; wp += sz;
        pyw[l] = wp; wp += sz;
    }
    const float* px[5] = {x0, pxw[1], pxw[2], pxw[3], pxw[4]};
    const float* py[5] = {y0, pyw[1], pyw[2], pyw[3], pyw[4]};

    // gaussian weights (softmax of -c^2/(2*sigma^2))
    GW gw;
    {
        double tmp[FILT], s = 0.0;
        for (int k = 0; k < FILT; k++) {
            double c = (double)k - (FILT - 1) / 2.0;
            tmp[k] = exp(-c * c / (2.0 * 1.5 * 1.5));
            s += tmp[k];
        }
        for (int k = 0; k < FILT; k++) gw.w[k] = (float)(tmp[k] / s);
    }

    init_acc<<<1, 256, 0, stream>>>(mm);
    long n4 = (long)NC * 512 * 512 / 4;
    minmax_kernel<<<2048, 256, 0, stream>>>((const float4*)y0, n4, mm);

    for (int l = 0; l < 5; l++) {
        int H = Hs[l];
        int Ho = H - (FILT - 1);
        int nstrips = (Ho + 63) / 64;
        int B = Bs[l];
        int nb = (Ho + B - 1) / B;
        int total_waves = NC * nstrips * nb;
        int grid = (total_waves + 3) / 4;
        int do_pool = (l < 4) ? 1 : 0;
        ssim_stream<<<grid, 256, 0, stream>>>(
            px[l], py[l], H, H, NC, nstrips, nb, B, mm,
            cs_sum + l * 32, ssim_sum + l * 32, gw,
            do_pool ? pxw[l + 1] : nullptr,
            do_pool ? pyw[l + 1] : nullptr, do_pool);
    }
    final_kernel<<<1, 64, 0, stream>>>(cs_sum, ssim_sum, out);
}